// Round 8
// baseline (627.584 us; speedup 1.0000x reference)
//
#include <hip/hip_runtime.h>

#define N_NODES 50000
#define N_EDGES 800000
#define F_IN 768
#define H1 200
#define H1P 208  // padded h row: 13 x 16 cols = 832 B = 13 cache lines
#define H2 20
#define NB_SCAN 196  // ceil(50000/256)
#define NT 13
#define KSTEPS 24  // 768/32

typedef unsigned short ushort_t;
typedef __attribute__((ext_vector_type(8))) short bf16x8;
typedef __attribute__((ext_vector_type(4))) float f32x4;

// ---------------------------------------------------------------------------
// Workspace layout (byte offsets):
//   0         cnt_dst   int[50000]   (zeroed)
//   200000    cnt_src   int[50000]   (zeroed)
//   400000    cursor    int[50000]   (zeroed)
//   600000    partials  int[256]
//   601024    row_start int[50000]
//   801024    dinv_in   f32[50000]
//   1001024   dinv_out  f32[50000]
//   1201024   src_s     int[800000]
//   4401024   w_s       f32[800000]
//   7601024   h         f32[50000*208]  (41.6 MB, padded rows)
//   49201024  g2        f32[1000000]
//   53201024  Bf        uint4[24*13*2*64]  (639 KB, fragment-ordered W1 hi/lo)
// total ~53.9 MB
// ---------------------------------------------------------------------------

__global__ __launch_bounds__(256) void k_count(const int* __restrict__ src,
                                               const int* __restrict__ dst,
                                               int* __restrict__ cnt_src,
                                               int* __restrict__ cnt_dst) {
  int i = blockIdx.x * 256 + threadIdx.x;
  if (i < N_EDGES) {
    atomicAdd(&cnt_src[src[i]], 1);
    atomicAdd(&cnt_dst[dst[i]], 1);
  }
}

__global__ __launch_bounds__(256) void k_scan_block(const int* __restrict__ cnt_dst,
                                                    int* __restrict__ row_start,
                                                    int* __restrict__ partials) {
  __shared__ int sm[256];
  int i = blockIdx.x * 256 + threadIdx.x;
  int v = (i < N_NODES) ? cnt_dst[i] : 0;
  sm[threadIdx.x] = v;
  __syncthreads();
#pragma unroll
  for (int off = 1; off < 256; off <<= 1) {
    int t = (threadIdx.x >= off) ? sm[threadIdx.x - off] : 0;
    __syncthreads();
    sm[threadIdx.x] += t;
    __syncthreads();
  }
  if (i < N_NODES) row_start[i] = sm[threadIdx.x] - v;  // exclusive
  if (threadIdx.x == 255) partials[blockIdx.x] = sm[255];
}

__global__ __launch_bounds__(256) void k_scan_partials(int* __restrict__ partials) {
  __shared__ int sm[256];
  int v = (threadIdx.x < NB_SCAN) ? partials[threadIdx.x] : 0;
  sm[threadIdx.x] = v;
  __syncthreads();
#pragma unroll
  for (int off = 1; off < 256; off <<= 1) {
    int t = (threadIdx.x >= off) ? sm[threadIdx.x - off] : 0;
    __syncthreads();
    sm[threadIdx.x] += t;
    __syncthreads();
  }
  partials[threadIdx.x] = sm[threadIdx.x] - v;
}

__global__ __launch_bounds__(256) void k_scan_add(const int* __restrict__ cnt_dst,
                                                  const int* __restrict__ cnt_src,
                                                  const int* __restrict__ partials,
                                                  int* __restrict__ row_start,
                                                  float* __restrict__ dinv_in,
                                                  float* __restrict__ dinv_out) {
  int i = blockIdx.x * 256 + threadIdx.x;
  if (i < N_NODES) {
    row_start[i] += partials[blockIdx.x];
    dinv_in[i] = rsqrtf(fmaxf((float)cnt_dst[i], 1.f));
    dinv_out[i] = rsqrtf(fmaxf((float)cnt_src[i], 1.f));
  }
}

__global__ __launch_bounds__(256) void k_fill(const int* __restrict__ src,
                                              const int* __restrict__ dst,
                                              const float* __restrict__ ew,
                                              const int* __restrict__ row_start,
                                              int* __restrict__ cursor,
                                              int* __restrict__ src_s,
                                              float* __restrict__ w_s) {
  int e = blockIdx.x * 256 + threadIdx.x;
  if (e < N_EDGES) {
    int d = dst[e];
    int pos = atomicAdd(&cursor[d], 1);
    int idx = row_start[d] + pos;
    src_s[idx] = src[e];
    w_s[idx] = ew[e];
  }
}

// ---------------- W1 -> fragment-ordered bf16 hi/lo ------------------------
// Bf[((ks*13 + nt)*2 + hl)*64 + lane] : uint4 = 8 bf16.
// lane l holds col = nt*16 + (l&15), k = ks*32 + (l>>4)*8 + 0..7.
__global__ __launch_bounds__(256) void k_splitW(const float* __restrict__ W1,
                                                uint4* __restrict__ Bf) {
  int idx = blockIdx.x * 256 + threadIdx.x;  // (ks*13+nt)*64 + lane
  if (idx >= KSTEPS * NT * 64) return;
  int lane = idx & 63;
  int tile = idx >> 6;  // ks*13 + nt
  int nt = tile % NT;
  int col = nt * 16 + (lane & 15);
  int k0 = (tile / NT) * 32 + (lane >> 4) * 8;
  unsigned hi[4], lo[4];
#pragma unroll
  for (int e = 0; e < 4; ++e) {
    float f0 = (col < H1) ? W1[(k0 + 2 * e) * H1 + col] : 0.f;
    float f1 = (col < H1) ? W1[(k0 + 2 * e + 1) * H1 + col] : 0.f;
    unsigned h0 = __float_as_uint(f0) >> 16;
    unsigned h1 = __float_as_uint(f1) >> 16;
    float l0 = f0 - __uint_as_float(h0 << 16);
    float l1 = f1 - __uint_as_float(h1 << 16);
    hi[e] = h0 | (h1 << 16);
    lo[e] = (__float_as_uint(l0) >> 16) | (__float_as_uint(l1) & 0xffff0000u);
  }
  uint4* p = &Bf[(size_t)(tile * 2) * 64 + lane];
  p[0] = make_uint4(hi[0], hi[1], hi[2], hi[3]);
  p[64] = make_uint4(lo[0], lo[1], lo[2], lo[3]);
}

// ---------------- GEMM1: barrier-free streaming MFMA -----------------------
// One 64-lane wave per block; each wave owns 32 rows (2 M-tiles) x all 13
// N-tiles. A fragments straight from global (lane l: row l&15 / 16+(l&15),
// k-quarter l>>4 -> wave covers 16 full 128B cache lines). B fragments from
// fragment-ordered Bf, one coalesced dwordx4 per lane. No LDS, no barriers.
__global__ __launch_bounds__(64) void k_gemm1_stream(
    const float* __restrict__ A,      // feature [50000][768]
    const uint4* __restrict__ Bf,     // fragment-ordered W1 hi/lo
    const float* __restrict__ dinv_out,
    float* __restrict__ H) {          // [50000][208]
  const int lane = threadIdx.x;
  const int bm = blockIdx.x * 32;
  const int fr = lane & 15;
  const int kq = lane >> 4;

  const int ar0 = bm + fr;
  const int ar1 = bm + 16 + fr;
  const bool ok0 = ar0 < N_NODES;
  const bool ok1 = ar1 < N_NODES;
  const float* __restrict__ pa0 = &A[(size_t)ar0 * F_IN + kq * 8];
  const float* __restrict__ pa1 = &A[(size_t)ar1 * F_IN + kq * 8];

  f32x4 acc0[NT], acc1[NT];
#pragma unroll
  for (int i = 0; i < NT; ++i) {
    acc0[i] = (f32x4)(0.f);
    acc1[i] = (f32x4)(0.f);
  }

  const float4 fz = make_float4(0.f, 0.f, 0.f, 0.f);
  float4 va0 = ok0 ? *(const float4*)(pa0) : fz;
  float4 va1 = ok0 ? *(const float4*)(pa0 + 4) : fz;
  float4 va2 = ok1 ? *(const float4*)(pa1) : fz;
  float4 va3 = ok1 ? *(const float4*)(pa1 + 4) : fz;

  for (int ks = 0; ks < KSTEPS; ++ks) {
    // convert 16 floats -> packed bf16 hi/lo (8 uints each of 2 rows)
    float fv[16] = {va0.x, va0.y, va0.z, va0.w, va1.x, va1.y, va1.z, va1.w,
                    va2.x, va2.y, va2.z, va2.w, va3.x, va3.y, va3.z, va3.w};
    unsigned hp[8], lp[8];
#pragma unroll
    for (int i = 0; i < 8; ++i) {
      unsigned b0 = __float_as_uint(fv[2 * i]);
      unsigned b1 = __float_as_uint(fv[2 * i + 1]);
      unsigned h0 = b0 >> 16, h1 = b1 >> 16;
      float l0 = fv[2 * i] - __uint_as_float(h0 << 16);
      float l1 = fv[2 * i + 1] - __uint_as_float(h1 << 16);
      hp[i] = h0 | (h1 << 16);
      lp[i] = (__float_as_uint(l0) >> 16) | (__float_as_uint(l1) & 0xffff0000u);
    }
    uint4 uH0 = make_uint4(hp[0], hp[1], hp[2], hp[3]);
    uint4 uL0 = make_uint4(lp[0], lp[1], lp[2], lp[3]);
    uint4 uH1 = make_uint4(hp[4], hp[5], hp[6], hp[7]);
    uint4 uL1 = make_uint4(lp[4], lp[5], lp[6], lp[7]);
    bf16x8 aH0 = *(bf16x8*)&uH0;
    bf16x8 aL0 = *(bf16x8*)&uL0;
    bf16x8 aH1 = *(bf16x8*)&uH1;
    bf16x8 aL1 = *(bf16x8*)&uL1;

    // prefetch next A k-step: latency hides under the nt loop below
    if (ks + 1 < KSTEPS) {
      int o = (ks + 1) * 32;
      va0 = ok0 ? *(const float4*)(pa0 + o) : fz;
      va1 = ok0 ? *(const float4*)(pa0 + o + 4) : fz;
      va2 = ok1 ? *(const float4*)(pa1 + o) : fz;
      va3 = ok1 ? *(const float4*)(pa1 + o + 4) : fz;
    }

    const uint4* __restrict__ bp = Bf + (size_t)(ks * NT * 2) * 64 + lane;
#pragma unroll
    for (int nt = 0; nt < NT; ++nt) {
      bf16x8 bH = *(const bf16x8*)&bp[nt * 128];
      bf16x8 bL = *(const bf16x8*)&bp[nt * 128 + 64];
      acc0[nt] = __builtin_amdgcn_mfma_f32_16x16x32_bf16(aH0, bH, acc0[nt], 0, 0, 0);
      acc0[nt] = __builtin_amdgcn_mfma_f32_16x16x32_bf16(aH0, bL, acc0[nt], 0, 0, 0);
      acc0[nt] = __builtin_amdgcn_mfma_f32_16x16x32_bf16(aL0, bH, acc0[nt], 0, 0, 0);
      acc1[nt] = __builtin_amdgcn_mfma_f32_16x16x32_bf16(aH1, bH, acc1[nt], 0, 0, 0);
      acc1[nt] = __builtin_amdgcn_mfma_f32_16x16x32_bf16(aH1, bL, acc1[nt], 0, 0, 0);
      acc1[nt] = __builtin_amdgcn_mfma_f32_16x16x32_bf16(aL1, bH, acc1[nt], 0, 0, 0);
    }
  }

  // epilogue: D row = kq*4 + rr (per M-tile), col = fr
  float d0[4], d1[4];
#pragma unroll
  for (int rr = 0; rr < 4; ++rr) {
    int g0 = bm + kq * 4 + rr;
    int g1 = bm + 16 + kq * 4 + rr;
    d0[rr] = (g0 < N_NODES) ? dinv_out[g0] : 0.f;
    d1[rr] = (g1 < N_NODES) ? dinv_out[g1] : 0.f;
  }
#pragma unroll
  for (int nt = 0; nt < NT; ++nt) {
    int gc = nt * 16 + fr;  // 0..207, pad cols written too
#pragma unroll
    for (int rr = 0; rr < 4; ++rr) {
      int g0 = bm + kq * 4 + rr;
      int g1 = bm + 16 + kq * 4 + rr;
      if (g0 < N_NODES) H[(size_t)g0 * H1P + gc] = acc0[nt][rr] * d0[rr];
      if (g1 < N_NODES) H[(size_t)g1 * H1P + gc] = acc1[nt][rr] * d1[rr];
    }
  }
}

// ---------------- layer1 fused: gather-agg + post + GEMM2 ------------------
__global__ __launch_bounds__(256) void k_layer1(
    const int* __restrict__ row_start, const int* __restrict__ cnt,
    const int* __restrict__ src_s, const float* __restrict__ w_s,
    const float* __restrict__ H, const float* __restrict__ dinv_in,
    const float* __restrict__ dinv_out, const float* __restrict__ b1,
    const float* __restrict__ W2, float* __restrict__ G) {
  __shared__ float Tsm[4][H1];
  const int wid = threadIdx.x >> 6;
  const int lane = threadIdx.x & 63;
  const int node = __builtin_amdgcn_readfirstlane(blockIdx.x * 4 + wid);
  const int start = __builtin_amdgcn_readfirstlane(row_start[node]);
  const int n = __builtin_amdgcn_readfirstlane(cnt[node]);
  const float4* __restrict__ Hv = (const float4*)H;
  const bool act = lane < (H1 / 4);
  float4 acc = make_float4(0.f, 0.f, 0.f, 0.f);

  int e = 0;
  for (; e + 2 <= n; e += 2) {
    int s0 = src_s[start + e];
    int s1 = src_s[start + e + 1];
    float w0 = w_s[start + e];
    float w1 = w_s[start + e + 1];
    if (act) {
      float4 u0 = Hv[(size_t)s0 * (H1P / 4) + lane];
      float4 u1 = Hv[(size_t)s1 * (H1P / 4) + lane];
      acc.x = fmaf(w0, u0.x, acc.x);
      acc.y = fmaf(w0, u0.y, acc.y);
      acc.z = fmaf(w0, u0.z, acc.z);
      acc.w = fmaf(w0, u0.w, acc.w);
      acc.x = fmaf(w1, u1.x, acc.x);
      acc.y = fmaf(w1, u1.y, acc.y);
      acc.z = fmaf(w1, u1.z, acc.z);
      acc.w = fmaf(w1, u1.w, acc.w);
    }
  }
  if (e < n) {
    int s0 = src_s[start + e];
    float w0 = w_s[start + e];
    if (act) {
      float4 u0 = Hv[(size_t)s0 * (H1P / 4) + lane];
      acc.x = fmaf(w0, u0.x, acc.x);
      acc.y = fmaf(w0, u0.y, acc.y);
      acc.z = fmaf(w0, u0.z, acc.z);
      acc.w = fmaf(w0, u0.w, acc.w);
    }
  }

  if (act) {
    float di = dinv_in[node];
    float dn = dinv_out[node];
    float4 bb = ((const float4*)b1)[lane];
    float4 r;
    r.x = fmaxf(fmaf(acc.x, di, bb.x), 0.f) * dn;
    r.y = fmaxf(fmaf(acc.y, di, bb.y), 0.f) * dn;
    r.z = fmaxf(fmaf(acc.z, di, bb.z), 0.f) * dn;
    r.w = fmaxf(fmaf(acc.w, di, bb.w), 0.f) * dn;
    *(float4*)&Tsm[wid][lane * 4] = r;
  }
  __syncthreads();

  if (lane < H2) {
    float a = 0.f;
#pragma unroll 8
    for (int d = 0; d < H1; ++d) a = fmaf(Tsm[wid][d], W2[d * H2 + lane], a);
    G[node * H2 + lane] = a;
  }
}

// ---------------- layer2: gather-agg + bias (no atomics) -------------------
__global__ __launch_bounds__(256) void k_agg2_final(
    const int* __restrict__ row_start, const int* __restrict__ cnt,
    const int* __restrict__ src_s, const float* __restrict__ w_s,
    const float* __restrict__ G, const float* __restrict__ dinv_in,
    const float* __restrict__ b2, float* __restrict__ out) {
  int gi = blockIdx.x * 256 + threadIdx.x;
  if (gi >= N_NODES * H2) return;
  int node = gi / H2;
  int dim = gi % H2;
  int start = row_start[node];
  int n = cnt[node];
  float acc = 0.f;
  int e = 0;
  for (; e + 2 <= n; e += 2) {
    int s0 = src_s[start + e];
    int s1 = src_s[start + e + 1];
    float w0 = w_s[start + e];
    float w1 = w_s[start + e + 1];
    float g0 = G[s0 * H2 + dim];
    float g1 = G[s1 * H2 + dim];
    acc = fmaf(w0, g0, acc);
    acc = fmaf(w1, g1, acc);
  }
  if (e < n) {
    int s0 = src_s[start + e];
    acc = fmaf(w_s[start + e], G[s0 * H2 + dim], acc);
  }
  out[gi] = fmaf(acc, dinv_in[node], b2[dim]);
}

extern "C" void kernel_launch(void* const* d_in, const int* in_sizes, int n_in,
                              void* d_out, int out_size, void* d_ws, size_t ws_size,
                              hipStream_t stream) {
  const float* feature = (const float*)d_in[0];
  const int* src = (const int*)d_in[1];
  const int* dst = (const int*)d_in[2];
  const float* edge_w = (const float*)d_in[3];
  const float* W1 = (const float*)d_in[4];
  const float* b1 = (const float*)d_in[5];
  const float* W2 = (const float*)d_in[6];
  const float* b2 = (const float*)d_in[7];
  float* out = (float*)d_out;

  char* wsb = (char*)d_ws;
  int* cnt_dst = (int*)(wsb + 0);
  int* cnt_src = (int*)(wsb + 200000);
  int* cursor = (int*)(wsb + 400000);
  int* partials = (int*)(wsb + 600000);
  int* row_start = (int*)(wsb + 601024);
  float* dinv_in = (float*)(wsb + 801024);
  float* dinv_out = (float*)(wsb + 1001024);
  int* src_s = (int*)(wsb + 1201024);
  float* w_s = (float*)(wsb + 4401024);
  float* h = (float*)(wsb + 7601024);
  float* g2 = (float*)(wsb + 49201024);
  uint4* Bf = (uint4*)(wsb + 53201024);

  hipMemsetAsync(wsb, 0, 600000, stream);

  k_count<<<(N_EDGES + 255) / 256, 256, 0, stream>>>(src, dst, cnt_src, cnt_dst);
  k_scan_block<<<NB_SCAN, 256, 0, stream>>>(cnt_dst, row_start, partials);
  k_scan_partials<<<1, 256, 0, stream>>>(partials);
  k_scan_add<<<NB_SCAN, 256, 0, stream>>>(cnt_dst, cnt_src, partials, row_start,
                                          dinv_in, dinv_out);
  k_fill<<<(N_EDGES + 255) / 256, 256, 0, stream>>>(src, dst, edge_w, row_start,
                                                    cursor, src_s, w_s);
  k_splitW<<<(KSTEPS * NT * 64 + 255) / 256, 256, 0, stream>>>(W1, Bf);

  k_gemm1_stream<<<(N_NODES + 31) / 32, 64, 0, stream>>>(feature, Bf, dinv_out, h);

  k_layer1<<<N_NODES / 4, 256, 0, stream>>>(row_start, cnt_dst, src_s, w_s, h,
                                            dinv_in, dinv_out, b1, W2, g2);
  k_agg2_final<<<(N_NODES * H2 + 255) / 256, 256, 0, stream>>>(
      row_start, cnt_dst, src_s, w_s, g2, dinv_in, b2, out);
}

// Round 9
// 582.834 us; speedup vs baseline: 1.0768x; 1.0768x over previous
//
#include <hip/hip_runtime.h>

#define N_NODES 50000
#define N_EDGES 800000
#define F_IN 768
#define H1 200
#define H1P 208  // padded h row: 13 x 16 cols = 832 B
#define H2 20
#define NB_SCAN 196  // ceil(50000/256)
#define NT 13

typedef unsigned short ushort_t;
typedef __attribute__((ext_vector_type(8))) short bf16x8;
typedef __attribute__((ext_vector_type(4))) float f32x4;

// ---------------------------------------------------------------------------
// Workspace layout (byte offsets):
//   0         cnt_dst   int[50000]   (zeroed)
//   200000    cnt_src   int[50000]   (zeroed)
//   400000    cursor    int[50000]   (zeroed)
//   600000    partials  int[256]
//   601024    row_start int[50000]
//   801024    dinv_in   f32[50000]
//   1001024   dinv_out  f32[50000]
//   1201024   src_s     int[800000]
//   4401024   w_s       f32[800000]
//   7601024   h         f32[50000*208]  (41.6 MB, padded rows)
//   49201024  g2        f32[1000000]
//   53201024  W1sH      u16[208*768]
//   53520512  W1sL      u16[208*768]
// ---------------------------------------------------------------------------

__global__ __launch_bounds__(256) void k_count(const int* __restrict__ src,
                                               const int* __restrict__ dst,
                                               int* __restrict__ cnt_src,
                                               int* __restrict__ cnt_dst) {
  int i = blockIdx.x * 256 + threadIdx.x;
  if (i < N_EDGES) {
    atomicAdd(&cnt_src[src[i]], 1);
    atomicAdd(&cnt_dst[dst[i]], 1);
  }
}

__global__ __launch_bounds__(256) void k_scan_block(const int* __restrict__ cnt_dst,
                                                    int* __restrict__ row_start,
                                                    int* __restrict__ partials) {
  __shared__ int sm[256];
  int i = blockIdx.x * 256 + threadIdx.x;
  int v = (i < N_NODES) ? cnt_dst[i] : 0;
  sm[threadIdx.x] = v;
  __syncthreads();
#pragma unroll
  for (int off = 1; off < 256; off <<= 1) {
    int t = (threadIdx.x >= off) ? sm[threadIdx.x - off] : 0;
    __syncthreads();
    sm[threadIdx.x] += t;
    __syncthreads();
  }
  if (i < N_NODES) row_start[i] = sm[threadIdx.x] - v;  // exclusive
  if (threadIdx.x == 255) partials[blockIdx.x] = sm[255];
}

__global__ __launch_bounds__(256) void k_scan_partials(int* __restrict__ partials) {
  __shared__ int sm[256];
  int v = (threadIdx.x < NB_SCAN) ? partials[threadIdx.x] : 0;
  sm[threadIdx.x] = v;
  __syncthreads();
#pragma unroll
  for (int off = 1; off < 256; off <<= 1) {
    int t = (threadIdx.x >= off) ? sm[threadIdx.x - off] : 0;
    __syncthreads();
    sm[threadIdx.x] += t;
    __syncthreads();
  }
  partials[threadIdx.x] = sm[threadIdx.x] - v;
}

__global__ __launch_bounds__(256) void k_scan_add(const int* __restrict__ cnt_dst,
                                                  const int* __restrict__ cnt_src,
                                                  const int* __restrict__ partials,
                                                  int* __restrict__ row_start,
                                                  float* __restrict__ dinv_in,
                                                  float* __restrict__ dinv_out) {
  int i = blockIdx.x * 256 + threadIdx.x;
  if (i < N_NODES) {
    row_start[i] += partials[blockIdx.x];
    dinv_in[i] = rsqrtf(fmaxf((float)cnt_dst[i], 1.f));
    dinv_out[i] = rsqrtf(fmaxf((float)cnt_src[i], 1.f));
  }
}

__global__ __launch_bounds__(256) void k_fill(const int* __restrict__ src,
                                              const int* __restrict__ dst,
                                              const float* __restrict__ ew,
                                              const int* __restrict__ row_start,
                                              int* __restrict__ cursor,
                                              int* __restrict__ src_s,
                                              float* __restrict__ w_s) {
  int e = blockIdx.x * 256 + threadIdx.x;
  if (e < N_EDGES) {
    int d = dst[e];
    int pos = atomicAdd(&cursor[d], 1);
    int idx = row_start[d] + pos;
    src_s[idx] = src[e];
    w_s[idx] = ew[e];
  }
}

// WH/WL layout: [208 cols][768 k], cols 200..207 zero-padded.
__global__ __launch_bounds__(256) void k_splitW(const float* __restrict__ W1,
                                                ushort_t* __restrict__ WH,
                                                ushort_t* __restrict__ WL) {
  int idx = blockIdx.x * 256 + threadIdx.x;
  if (idx >= 208 * F_IN) return;
  int col = idx / F_IN, k = idx % F_IN;
  float f = (col < H1) ? W1[k * H1 + col] : 0.f;
  unsigned b = __float_as_uint(f);
  unsigned h = b >> 16;
  float lo = f - __uint_as_float(h << 16);
  WH[idx] = (ushort_t)h;
  WL[idx] = (ushort_t)(__float_as_uint(lo) >> 16);
}

// ---------------- GEMM1 via split-bf16 MFMA, v3 ----------------------------
// BM=64 (4 waves x one 16-row M-tile each, all 13 N-tiles per wave) +
// slot-rotation swizzle (round-6, conflict-free) + A-register prefetch.
__global__ __launch_bounds__(256) void k_gemm1_mfma(
    const float* __restrict__ A,      // feature [50000][768]
    const ushort_t* __restrict__ BH,  // [208][768] bf16-hi of W1^T
    const ushort_t* __restrict__ BL,  // [208][768] bf16-lo
    const float* __restrict__ dinv_out,
    float* __restrict__ H) {          // [50000][208]
  __shared__ ushort_t AsH[64][32];
  __shared__ ushort_t AsL[64][32];
  __shared__ ushort_t BsH[NT][16][32];
  __shared__ ushort_t BsL[NT][16][32];

  const int t = threadIdx.x;
  const int wid = t >> 6;
  const int lane = t & 63;
  const int bm = blockIdx.x * 64;

  // A staging: 256 threads x 8 floats = 64x32 tile
  const int arow = t >> 2;  // 0..63
  const int akq = t & 3;
  const int aslot = (akq + ((arow >> 1) & 3)) & 3;
  const int agr = bm + arow;
  const float* __restrict__ arowp = &A[(size_t)agr * F_IN + akq * 8];

  // fragment geometry
  const int frow = lane & 15;
  const int kq = lane >> 4;  // 0..3
  const int row_local = wid * 16 + frow;
  const int arslot = (kq + ((row_local >> 1) & 3)) & 3;
  const int brslot = (kq + ((frow >> 1) & 3)) & 3;

  // B global_load_lds per-lane source mapping (inverse of slot swizzle):
  // lane l writes physical chunk l = f*4 + slot; logical q = (slot - (f>>1))&3
  const int bf = lane >> 2;
  const int bq = ((lane & 3) - ((lane >> 3) & 3)) & 3;

  f32x4 acc[NT];
#pragma unroll
  for (int i = 0; i < NT; ++i) acc[i] = (f32x4)(0.f);

  // prefetch A for k0 = 0
  const float4 fz = make_float4(0.f, 0.f, 0.f, 0.f);
  float4 v0 = fz, v1 = fz;
  if (agr < N_NODES) {
    v0 = *(const float4*)&arowp[0];
    v1 = *(const float4*)&arowp[4];
  }

  for (int k0 = 0; k0 < F_IN; k0 += 32) {
    // convert current A regs to packed bf16 hi/lo
    float fv[8] = {v0.x, v0.y, v0.z, v0.w, v1.x, v1.y, v1.z, v1.w};
    unsigned hp[4], lp[4];
#pragma unroll
    for (int i = 0; i < 4; ++i) {
      unsigned b0 = __float_as_uint(fv[2 * i]);
      unsigned b1 = __float_as_uint(fv[2 * i + 1]);
      unsigned h0 = b0 >> 16, h1 = b1 >> 16;
      float lo0 = fv[2 * i] - __uint_as_float(h0 << 16);
      float lo1 = fv[2 * i + 1] - __uint_as_float(h1 << 16);
      hp[i] = h0 | (h1 << 16);
      lp[i] = (__float_as_uint(lo0) >> 16) | (__float_as_uint(lo1) & 0xffff0000u);
    }

    __syncthreads();  // previous iteration's fragment reads done

    *(uint4*)&AsH[arow][aslot * 8] = make_uint4(hp[0], hp[1], hp[2], hp[3]);
    *(uint4*)&AsL[arow][aslot * 8] = make_uint4(lp[0], lp[1], lp[2], lp[3]);

    // B tiles via global_load_lds (16B/lane, linear dest, pre-swizzled src)
    for (int nt = wid; nt < NT; nt += 4) {
      const ushort_t* gh = &BH[(size_t)(nt * 16 + bf) * F_IN + k0 + bq * 8];
      const ushort_t* gl = &BL[(size_t)(nt * 16 + bf) * F_IN + k0 + bq * 8];
      __builtin_amdgcn_global_load_lds(gh, &BsH[nt][0][0], 16, 0, 0);
      __builtin_amdgcn_global_load_lds(gl, &BsL[nt][0][0], 16, 0, 0);
    }

    // prefetch next A tile (drains in the same vmcnt(0) as the B loads)
    v0 = fz;
    v1 = fz;
    if (k0 + 32 < F_IN && agr < N_NODES) {
      v0 = *(const float4*)&arowp[k0 + 32];
      v1 = *(const float4*)&arowp[k0 + 36];
    }

    __syncthreads();  // LDS writes + async B loads visible

    bf16x8 aH = *(const bf16x8*)&AsH[row_local][arslot * 8];
    bf16x8 aL = *(const bf16x8*)&AsL[row_local][arslot * 8];
#pragma unroll
    for (int nt = 0; nt < NT; ++nt) {
      bf16x8 bH = *(const bf16x8*)&BsH[nt][frow][brslot * 8];
      bf16x8 bL = *(const bf16x8*)&BsL[nt][frow][brslot * 8];
      acc[nt] = __builtin_amdgcn_mfma_f32_16x16x32_bf16(aH, bH, acc[nt], 0, 0, 0);
      acc[nt] = __builtin_amdgcn_mfma_f32_16x16x32_bf16(aH, bL, acc[nt], 0, 0, 0);
      acc[nt] = __builtin_amdgcn_mfma_f32_16x16x32_bf16(aL, bH, acc[nt], 0, 0, 0);
    }
  }

  // epilogue: D row = wid*16 + kq*4 + r, col = frow
  const int r0 = bm + wid * 16 + kq * 4;
  float dsc[4];
#pragma unroll
  for (int r = 0; r < 4; ++r)
    dsc[r] = (r0 + r < N_NODES) ? dinv_out[r0 + r] : 0.f;
#pragma unroll
  for (int nt = 0; nt < NT; ++nt) {
    int gc = nt * 16 + frow;  // 0..207, pad cols written too
#pragma unroll
    for (int r = 0; r < 4; ++r) {
      int gr = r0 + r;
      if (gr < N_NODES) H[(size_t)gr * H1P + gc] = acc[nt][r] * dsc[r];
    }
  }
}

// ---------------- layer1 fused: gather-agg + post + GEMM2 ------------------
__global__ __launch_bounds__(256) void k_layer1(
    const int* __restrict__ row_start, const int* __restrict__ cnt,
    const int* __restrict__ src_s, const float* __restrict__ w_s,
    const float* __restrict__ H, const float* __restrict__ dinv_in,
    const float* __restrict__ dinv_out, const float* __restrict__ b1,
    const float* __restrict__ W2, float* __restrict__ G) {
  __shared__ float Tsm[4][H1];
  const int wid = threadIdx.x >> 6;
  const int lane = threadIdx.x & 63;
  const int node = __builtin_amdgcn_readfirstlane(blockIdx.x * 4 + wid);
  const int start = __builtin_amdgcn_readfirstlane(row_start[node]);
  const int n = __builtin_amdgcn_readfirstlane(cnt[node]);
  const float4* __restrict__ Hv = (const float4*)H;
  const bool act = lane < (H1 / 4);
  float4 acc = make_float4(0.f, 0.f, 0.f, 0.f);

  int e = 0;
  for (; e + 2 <= n; e += 2) {
    int s0 = src_s[start + e];
    int s1 = src_s[start + e + 1];
    float w0 = w_s[start + e];
    float w1 = w_s[start + e + 1];
    if (act) {
      float4 u0 = Hv[(size_t)s0 * (H1P / 4) + lane];
      float4 u1 = Hv[(size_t)s1 * (H1P / 4) + lane];
      acc.x = fmaf(w0, u0.x, acc.x);
      acc.y = fmaf(w0, u0.y, acc.y);
      acc.z = fmaf(w0, u0.z, acc.z);
      acc.w = fmaf(w0, u0.w, acc.w);
      acc.x = fmaf(w1, u1.x, acc.x);
      acc.y = fmaf(w1, u1.y, acc.y);
      acc.z = fmaf(w1, u1.z, acc.z);
      acc.w = fmaf(w1, u1.w, acc.w);
    }
  }
  if (e < n) {
    int s0 = src_s[start + e];
    float w0 = w_s[start + e];
    if (act) {
      float4 u0 = Hv[(size_t)s0 * (H1P / 4) + lane];
      acc.x = fmaf(w0, u0.x, acc.x);
      acc.y = fmaf(w0, u0.y, acc.y);
      acc.z = fmaf(w0, u0.z, acc.z);
      acc.w = fmaf(w0, u0.w, acc.w);
    }
  }

  if (act) {
    float di = dinv_in[node];
    float dn = dinv_out[node];
    float4 bb = ((const float4*)b1)[lane];
    float4 r;
    r.x = fmaxf(fmaf(acc.x, di, bb.x), 0.f) * dn;
    r.y = fmaxf(fmaf(acc.y, di, bb.y), 0.f) * dn;
    r.z = fmaxf(fmaf(acc.z, di, bb.z), 0.f) * dn;
    r.w = fmaxf(fmaf(acc.w, di, bb.w), 0.f) * dn;
    *(float4*)&Tsm[wid][lane * 4] = r;
  }
  __syncthreads();

  if (lane < H2) {
    float a = 0.f;
#pragma unroll 8
    for (int d = 0; d < H1; ++d) a = fmaf(Tsm[wid][d], W2[d * H2 + lane], a);
    G[node * H2 + lane] = a;
  }
}

// ---------------- layer2: gather-agg + bias (no atomics) -------------------
__global__ __launch_bounds__(256) void k_agg2_final(
    const int* __restrict__ row_start, const int* __restrict__ cnt,
    const int* __restrict__ src_s, const float* __restrict__ w_s,
    const float* __restrict__ G, const float* __restrict__ dinv_in,
    const float* __restrict__ b2, float* __restrict__ out) {
  int gi = blockIdx.x * 256 + threadIdx.x;
  if (gi >= N_NODES * H2) return;
  int node = gi / H2;
  int dim = gi % H2;
  int start = row_start[node];
  int n = cnt[node];
  float acc = 0.f;
  int e = 0;
  for (; e + 2 <= n; e += 2) {
    int s0 = src_s[start + e];
    int s1 = src_s[start + e + 1];
    float w0 = w_s[start + e];
    float w1 = w_s[start + e + 1];
    float g0 = G[s0 * H2 + dim];
    float g1 = G[s1 * H2 + dim];
    acc = fmaf(w0, g0, acc);
    acc = fmaf(w1, g1, acc);
  }
  if (e < n) {
    int s0 = src_s[start + e];
    acc = fmaf(w_s[start + e], G[s0 * H2 + dim], acc);
  }
  out[gi] = fmaf(acc, dinv_in[node], b2[dim]);
}

extern "C" void kernel_launch(void* const* d_in, const int* in_sizes, int n_in,
                              void* d_out, int out_size, void* d_ws, size_t ws_size,
                              hipStream_t stream) {
  const float* feature = (const float*)d_in[0];
  const int* src = (const int*)d_in[1];
  const int* dst = (const int*)d_in[2];
  const float* edge_w = (const float*)d_in[3];
  const float* W1 = (const float*)d_in[4];
  const float* b1 = (const float*)d_in[5];
  const float* W2 = (const float*)d_in[6];
  const float* b2 = (const float*)d_in[7];
  float* out = (float*)d_out;

  char* wsb = (char*)d_ws;
  int* cnt_dst = (int*)(wsb + 0);
  int* cnt_src = (int*)(wsb + 200000);
  int* cursor = (int*)(wsb + 400000);
  int* partials = (int*)(wsb + 600000);
  int* row_start = (int*)(wsb + 601024);
  float* dinv_in = (float*)(wsb + 801024);
  float* dinv_out = (float*)(wsb + 1001024);
  int* src_s = (int*)(wsb + 1201024);
  float* w_s = (float*)(wsb + 4401024);
  float* h = (float*)(wsb + 7601024);
  float* g2 = (float*)(wsb + 49201024);
  ushort_t* W1sH = (ushort_t*)(wsb + 53201024);
  ushort_t* W1sL = (ushort_t*)(wsb + 53520512);

  hipMemsetAsync(wsb, 0, 600000, stream);

  k_count<<<(N_EDGES + 255) / 256, 256, 0, stream>>>(src, dst, cnt_src, cnt_dst);
  k_scan_block<<<NB_SCAN, 256, 0, stream>>>(cnt_dst, row_start, partials);
  k_scan_partials<<<1, 256, 0, stream>>>(partials);
  k_scan_add<<<NB_SCAN, 256, 0, stream>>>(cnt_dst, cnt_src, partials, row_start,
                                          dinv_in, dinv_out);
  k_fill<<<(N_EDGES + 255) / 256, 256, 0, stream>>>(src, dst, edge_w, row_start,
                                                    cursor, src_s, w_s);
  k_splitW<<<(208 * F_IN + 255) / 256, 256, 0, stream>>>(W1, W1sH, W1sL);

  k_gemm1_mfma<<<(N_NODES + 63) / 64, 256, 0, stream>>>(feature, W1sH, W1sL,
                                                        dinv_out, h);

  k_layer1<<<N_NODES / 4, 256, 0, stream>>>(row_start, cnt_dst, src_s, w_s, h,
                                            dinv_in, dinv_out, b1, W2, g2);
  k_agg2_final<<<(N_NODES * H2 + 255) / 256, 256, 0, stream>>>(
      row_start, cnt_dst, src_s, w_s, g2, dinv_in, b2, out);
}

// Round 14
// 548.985 us; speedup vs baseline: 1.1432x; 1.0617x over previous
//
#include <hip/hip_runtime.h>

#define N_NODES 50000
#define N_EDGES 800000
#define F_IN 768
#define H1 200
#define H1P 208  // padded h row: 13 x 16 cols = 832 B
#define H2 20
#define NB_SCAN 196  // ceil(50000/256)
#define NT 13

typedef unsigned short ushort_t;
typedef __attribute__((ext_vector_type(8))) short bf16x8;
typedef __attribute__((ext_vector_type(4))) float f32x4;

// ---------------------------------------------------------------------------
// Workspace layout (byte offsets):
//   0         cnt_dst   int[50000]   (zeroed)
//   200000    cnt_src   int[50000]   (zeroed)
//   400000    cursor    int[50000]   (zeroed)
//   600000    partials  int[256]
//   601024    row_start int[50000]
//   801024    dinv_in   f32[50000]
//   1001024   dinv_out  f32[50000]
//   1201024   src_s     int[800000]
//   4401024   w_s       f32[800000]
//   7601024   h         f32[50000*208]  (41.6 MB, padded rows)
//   49201024  g2        f32[1000000]
//   53201024  W1sH      u16[208*768]
//   53520512  W1sL      u16[208*768]
// ---------------------------------------------------------------------------

__global__ __launch_bounds__(256) void k_count(const int* __restrict__ src,
                                               const int* __restrict__ dst,
                                               int* __restrict__ cnt_src,
                                               int* __restrict__ cnt_dst) {
  int i = blockIdx.x * 256 + threadIdx.x;
  if (i < N_EDGES) {
    atomicAdd(&cnt_src[src[i]], 1);
    atomicAdd(&cnt_dst[dst[i]], 1);
  }
}

__global__ __launch_bounds__(256) void k_scan_block(const int* __restrict__ cnt_dst,
                                                    int* __restrict__ row_start,
                                                    int* __restrict__ partials) {
  __shared__ int sm[256];
  int i = blockIdx.x * 256 + threadIdx.x;
  int v = (i < N_NODES) ? cnt_dst[i] : 0;
  sm[threadIdx.x] = v;
  __syncthreads();
#pragma unroll
  for (int off = 1; off < 256; off <<= 1) {
    int t = (threadIdx.x >= off) ? sm[threadIdx.x - off] : 0;
    __syncthreads();
    sm[threadIdx.x] += t;
    __syncthreads();
  }
  if (i < N_NODES) row_start[i] = sm[threadIdx.x] - v;  // exclusive
  if (threadIdx.x == 255) partials[blockIdx.x] = sm[255];
}

__global__ __launch_bounds__(256) void k_scan_partials(int* __restrict__ partials) {
  __shared__ int sm[256];
  int v = (threadIdx.x < NB_SCAN) ? partials[threadIdx.x] : 0;
  sm[threadIdx.x] = v;
  __syncthreads();
#pragma unroll
  for (int off = 1; off < 256; off <<= 1) {
    int t = (threadIdx.x >= off) ? sm[threadIdx.x - off] : 0;
    __syncthreads();
    sm[threadIdx.x] += t;
    __syncthreads();
  }
  partials[threadIdx.x] = sm[threadIdx.x] - v;
}

__global__ __launch_bounds__(256) void k_scan_add(const int* __restrict__ cnt_dst,
                                                  const int* __restrict__ cnt_src,
                                                  const int* __restrict__ partials,
                                                  int* __restrict__ row_start,
                                                  float* __restrict__ dinv_in,
                                                  float* __restrict__ dinv_out) {
  int i = blockIdx.x * 256 + threadIdx.x;
  if (i < N_NODES) {
    row_start[i] += partials[blockIdx.x];
    dinv_in[i] = rsqrtf(fmaxf((float)cnt_dst[i], 1.f));
    dinv_out[i] = rsqrtf(fmaxf((float)cnt_src[i], 1.f));
  }
}

__global__ __launch_bounds__(256) void k_fill(const int* __restrict__ src,
                                              const int* __restrict__ dst,
                                              const float* __restrict__ ew,
                                              const int* __restrict__ row_start,
                                              int* __restrict__ cursor,
                                              int* __restrict__ src_s,
                                              float* __restrict__ w_s) {
  int e = blockIdx.x * 256 + threadIdx.x;
  if (e < N_EDGES) {
    int d = dst[e];
    int pos = atomicAdd(&cursor[d], 1);
    int idx = row_start[d] + pos;
    src_s[idx] = src[e];
    w_s[idx] = ew[e];
  }
}

// WH/WL layout: [208 cols][768 k], cols 200..207 zero-padded.
__global__ __launch_bounds__(256) void k_splitW(const float* __restrict__ W1,
                                                ushort_t* __restrict__ WH,
                                                ushort_t* __restrict__ WL) {
  int idx = blockIdx.x * 256 + threadIdx.x;
  if (idx >= 208 * F_IN) return;
  int col = idx / F_IN, k = idx % F_IN;
  float f = (col < H1) ? W1[k * H1 + col] : 0.f;
  unsigned b = __float_as_uint(f);
  unsigned h = b >> 16;
  float lo = f - __uint_as_float(h << 16);
  WH[idx] = (ushort_t)h;
  WL[idx] = (ushort_t)(__float_as_uint(lo) >> 16);
}

// ---------------- GEMM1 via split-bf16 MFMA, v4 ----------------------------
// BK=64 (12 K-steps -> half the barrier drains), NO A-LDS (fragments loaded
// straight from global per lane, zero duplication), B-only LDS (53KB) with
// 8-slot rotation swizzle (phys=(q+row)&7) applied on gll SOURCE and read.
__global__ __launch_bounds__(256) void k_gemm1_mfma(
    const float* __restrict__ A,      // feature [50000][768]
    const ushort_t* __restrict__ BH,  // [208][768] bf16-hi of W1^T
    const ushort_t* __restrict__ BL,  // [208][768] bf16-lo
    const float* __restrict__ dinv_out,
    float* __restrict__ H) {          // [50000][208]
  __shared__ ushort_t BsH[NT][16][64];
  __shared__ ushort_t BsL[NT][16][64];

  const int t = threadIdx.x;
  const int wid = t >> 6;
  const int lane = t & 63;
  const int bm = blockIdx.x * 64;

  // fragment geometry (wave owns rows bm+wid*16 .. +15, all 13 N-tiles)
  const int frow = lane & 15;
  const int kq = lane >> 4;  // 0..3
  const int agr = bm + wid * 16 + frow;
  const bool ok = agr < N_NODES;
  const float* __restrict__ ap = &A[(size_t)agr * F_IN + kq * 8];

  // B gll source pre-swizzle: instr half h2 writes rows h2*8+(l>>3);
  // phys slot = l&7 holds logical k-slot q = ((l&7) - (l>>3)) & 7.
  const int brow = lane >> 3;              // 0..7 (row within 8-row half)
  const int bq = ((lane & 7) - brow) & 7;  // logical 16B k-slot

  // read-side phys slots for logical slots kq (half0) and 4+kq (half1)
  const int p0 = ((kq + frow) & 7) * 8;
  const int p1 = ((kq + 4 + frow) & 7) * 8;

  f32x4 acc[NT];
#pragma unroll
  for (int i = 0; i < NT; ++i) acc[i] = (f32x4)(0.f);

  const float4 fz = make_float4(0.f, 0.f, 0.f, 0.f);
  float4 c0 = fz, c1 = fz, c2 = fz, c3 = fz;
  if (ok) {
    c0 = *(const float4*)(ap + 0);
    c1 = *(const float4*)(ap + 4);
    c2 = *(const float4*)(ap + 32);
    c3 = *(const float4*)(ap + 36);
  }

  for (int k0 = 0; k0 < F_IN; k0 += 64) {
    // convert current A regs (16 floats = two K-halves) to bf16 hi/lo
    float fv[16] = {c0.x, c0.y, c0.z, c0.w, c1.x, c1.y, c1.z, c1.w,
                    c2.x, c2.y, c2.z, c2.w, c3.x, c3.y, c3.z, c3.w};
    unsigned hp[8], lp[8];
#pragma unroll
    for (int i = 0; i < 8; ++i) {
      unsigned b0 = __float_as_uint(fv[2 * i]);
      unsigned b1 = __float_as_uint(fv[2 * i + 1]);
      unsigned h0 = b0 >> 16, h1 = b1 >> 16;
      float l0 = fv[2 * i] - __uint_as_float(h0 << 16);
      float l1 = fv[2 * i + 1] - __uint_as_float(h1 << 16);
      hp[i] = h0 | (h1 << 16);
      lp[i] = (__float_as_uint(l0) >> 16) | (__float_as_uint(l1) & 0xffff0000u);
    }
    uint4 uH0 = make_uint4(hp[0], hp[1], hp[2], hp[3]);
    uint4 uL0 = make_uint4(lp[0], lp[1], lp[2], lp[3]);
    uint4 uH1 = make_uint4(hp[4], hp[5], hp[6], hp[7]);
    uint4 uL1 = make_uint4(lp[4], lp[5], lp[6], lp[7]);
    bf16x8 aH0 = *(bf16x8*)&uH0;
    bf16x8 aL0 = *(bf16x8*)&uL0;
    bf16x8 aH1 = *(bf16x8*)&uH1;
    bf16x8 aL1 = *(bf16x8*)&uL1;

    __syncthreads();  // previous iteration's B ds_reads complete

    // B tiles via global_load_lds: per (nt): 2 halves x {hi,lo} = 4 x 1KB
    for (int nt = wid; nt < NT; nt += 4) {
#pragma unroll
      for (int h2 = 0; h2 < 2; ++h2) {
        const ushort_t* gh =
            &BH[(size_t)(nt * 16 + h2 * 8 + brow) * F_IN + k0 + bq * 8];
        const ushort_t* gl =
            &BL[(size_t)(nt * 16 + h2 * 8 + brow) * F_IN + k0 + bq * 8];
        __builtin_amdgcn_global_load_lds(gh, &BsH[nt][h2 * 8][0], 16, 0, 0);
        __builtin_amdgcn_global_load_lds(gl, &BsL[nt][h2 * 8][0], 16, 0, 0);
      }
    }

    // prefetch next A K-step (drains in the same vmcnt(0) as the B loads)
    c0 = fz; c1 = fz; c2 = fz; c3 = fz;
    if (k0 + 64 < F_IN && ok) {
      c0 = *(const float4*)(ap + k0 + 64);
      c1 = *(const float4*)(ap + k0 + 68);
      c2 = *(const float4*)(ap + k0 + 96);
      c3 = *(const float4*)(ap + k0 + 100);
    }

    __syncthreads();  // B LDS visible

#pragma unroll
    for (int nt = 0; nt < NT; ++nt) {
      bf16x8 bH0 = *(const bf16x8*)&BsH[nt][frow][p0];
      bf16x8 bL0 = *(const bf16x8*)&BsL[nt][frow][p0];
      bf16x8 bH1 = *(const bf16x8*)&BsH[nt][frow][p1];
      bf16x8 bL1 = *(const bf16x8*)&BsL[nt][frow][p1];
      acc[nt] = __builtin_amdgcn_mfma_f32_16x16x32_bf16(aH0, bH0, acc[nt], 0, 0, 0);
      acc[nt] = __builtin_amdgcn_mfma_f32_16x16x32_bf16(aH0, bL0, acc[nt], 0, 0, 0);
      acc[nt] = __builtin_amdgcn_mfma_f32_16x16x32_bf16(aL0, bH0, acc[nt], 0, 0, 0);
      acc[nt] = __builtin_amdgcn_mfma_f32_16x16x32_bf16(aH1, bH1, acc[nt], 0, 0, 0);
      acc[nt] = __builtin_amdgcn_mfma_f32_16x16x32_bf16(aH1, bL1, acc[nt], 0, 0, 0);
      acc[nt] = __builtin_amdgcn_mfma_f32_16x16x32_bf16(aL1, bH1, acc[nt], 0, 0, 0);
    }
  }

  // epilogue: D row = wid*16 + kq*4 + r, col = frow
  const int r0 = bm + wid * 16 + kq * 4;
  float dsc[4];
#pragma unroll
  for (int r = 0; r < 4; ++r)
    dsc[r] = (r0 + r < N_NODES) ? dinv_out[r0 + r] : 0.f;
#pragma unroll
  for (int nt = 0; nt < NT; ++nt) {
    int gc = nt * 16 + frow;  // 0..207, pad cols written too
#pragma unroll
    for (int r = 0; r < 4; ++r) {
      int gr = r0 + r;
      if (gr < N_NODES) H[(size_t)gr * H1P + gc] = acc[nt][r] * dsc[r];
    }
  }
}

// ---------------- layer1 fused: gather-agg + post + GEMM2 ------------------
__global__ __launch_bounds__(256) void k_layer1(
    const int* __restrict__ row_start, const int* __restrict__ cnt,
    const int* __restrict__ src_s, const float* __restrict__ w_s,
    const float* __restrict__ H, const float* __restrict__ dinv_in,
    const float* __restrict__ dinv_out, const float* __restrict__ b1,
    const float* __restrict__ W2, float* __restrict__ G) {
  __shared__ float Tsm[4][H1];
  const int wid = threadIdx.x >> 6;
  const int lane = threadIdx.x & 63;
  const int node = __builtin_amdgcn_readfirstlane(blockIdx.x * 4 + wid);
  const int start = __builtin_amdgcn_readfirstlane(row_start[node]);
  const int n = __builtin_amdgcn_readfirstlane(cnt[node]);
  const float4* __restrict__ Hv = (const float4*)H;
  const bool act = lane < (H1 / 4);
  float4 acc = make_float4(0.f, 0.f, 0.f, 0.f);

  int e = 0;
  for (; e + 2 <= n; e += 2) {
    int s0 = src_s[start + e];
    int s1 = src_s[start + e + 1];
    float w0 = w_s[start + e];
    float w1 = w_s[start + e + 1];
    if (act) {
      float4 u0 = Hv[(size_t)s0 * (H1P / 4) + lane];
      float4 u1 = Hv[(size_t)s1 * (H1P / 4) + lane];
      acc.x = fmaf(w0, u0.x, acc.x);
      acc.y = fmaf(w0, u0.y, acc.y);
      acc.z = fmaf(w0, u0.z, acc.z);
      acc.w = fmaf(w0, u0.w, acc.w);
      acc.x = fmaf(w1, u1.x, acc.x);
      acc.y = fmaf(w1, u1.y, acc.y);
      acc.z = fmaf(w1, u1.z, acc.z);
      acc.w = fmaf(w1, u1.w, acc.w);
    }
  }
  if (e < n) {
    int s0 = src_s[start + e];
    float w0 = w_s[start + e];
    if (act) {
      float4 u0 = Hv[(size_t)s0 * (H1P / 4) + lane];
      acc.x = fmaf(w0, u0.x, acc.x);
      acc.y = fmaf(w0, u0.y, acc.y);
      acc.z = fmaf(w0, u0.z, acc.z);
      acc.w = fmaf(w0, u0.w, acc.w);
    }
  }

  if (act) {
    float di = dinv_in[node];
    float dn = dinv_out[node];
    float4 bb = ((const float4*)b1)[lane];
    float4 r;
    r.x = fmaxf(fmaf(acc.x, di, bb.x), 0.f) * dn;
    r.y = fmaxf(fmaf(acc.y, di, bb.y), 0.f) * dn;
    r.z = fmaxf(fmaf(acc.z, di, bb.z), 0.f) * dn;
    r.w = fmaxf(fmaf(acc.w, di, bb.w), 0.f) * dn;
    *(float4*)&Tsm[wid][lane * 4] = r;
  }
  __syncthreads();

  if (lane < H2) {
    float a = 0.f;
#pragma unroll 8
    for (int d = 0; d < H1; ++d) a = fmaf(Tsm[wid][d], W2[d * H2 + lane], a);
    G[node * H2 + lane] = a;
  }
}

// ---------------- layer2: gather-agg + bias (no atomics) -------------------
__global__ __launch_bounds__(256) void k_agg2_final(
    const int* __restrict__ row_start, const int* __restrict__ cnt,
    const int* __restrict__ src_s, const float* __restrict__ w_s,
    const float* __restrict__ G, const float* __restrict__ dinv_in,
    const float* __restrict__ b2, float* __restrict__ out) {
  int gi = blockIdx.x * 256 + threadIdx.x;
  if (gi >= N_NODES * H2) return;
  int node = gi / H2;
  int dim = gi % H2;
  int start = row_start[node];
  int n = cnt[node];
  float acc = 0.f;
  int e = 0;
  for (; e + 2 <= n; e += 2) {
    int s0 = src_s[start + e];
    int s1 = src_s[start + e + 1];
    float w0 = w_s[start + e];
    float w1 = w_s[start + e + 1];
    float g0 = G[s0 * H2 + dim];
    float g1 = G[s1 * H2 + dim];
    acc = fmaf(w0, g0, acc);
    acc = fmaf(w1, g1, acc);
  }
  if (e < n) {
    int s0 = src_s[start + e];
    acc = fmaf(w_s[start + e], G[s0 * H2 + dim], acc);
  }
  out[gi] = fmaf(acc, dinv_in[node], b2[dim]);
}

extern "C" void kernel_launch(void* const* d_in, const int* in_sizes, int n_in,
                              void* d_out, int out_size, void* d_ws, size_t ws_size,
                              hipStream_t stream) {
  const float* feature = (const float*)d_in[0];
  const int* src = (const int*)d_in[1];
  const int* dst = (const int*)d_in[2];
  const float* edge_w = (const float*)d_in[3];
  const float* W1 = (const float*)d_in[4];
  const float* b1 = (const float*)d_in[5];
  const float* W2 = (const float*)d_in[6];
  const float* b2 = (const float*)d_in[7];
  float* out = (float*)d_out;

  char* wsb = (char*)d_ws;
  int* cnt_dst = (int*)(wsb + 0);
  int* cnt_src = (int*)(wsb + 200000);
  int* cursor = (int*)(wsb + 400000);
  int* partials = (int*)(wsb + 600000);
  int* row_start = (int*)(wsb + 601024);
  float* dinv_in = (float*)(wsb + 801024);
  float* dinv_out = (float*)(wsb + 1001024);
  int* src_s = (int*)(wsb + 1201024);
  float* w_s = (float*)(wsb + 4401024);
  float* h = (float*)(wsb + 7601024);
  float* g2 = (float*)(wsb + 49201024);
  ushort_t* W1sH = (ushort_t*)(wsb + 53201024);
  ushort_t* W1sL = (ushort_t*)(wsb + 53520512);

  hipMemsetAsync(wsb, 0, 600000, stream);

  k_count<<<(N_EDGES + 255) / 256, 256, 0, stream>>>(src, dst, cnt_src, cnt_dst);
  k_scan_block<<<NB_SCAN, 256, 0, stream>>>(cnt_dst, row_start, partials);
  k_scan_partials<<<1, 256, 0, stream>>>(partials);
  k_scan_add<<<NB_SCAN, 256, 0, stream>>>(cnt_dst, cnt_src, partials, row_start,
                                          dinv_in, dinv_out);
  k_fill<<<(N_EDGES + 255) / 256, 256, 0, stream>>>(src, dst, edge_w, row_start,
                                                    cursor, src_s, w_s);
  k_splitW<<<(208 * F_IN + 255) / 256, 256, 0, stream>>>(W1, W1sH, W1sL);

  k_gemm1_mfma<<<(N_NODES + 63) / 64, 256, 0, stream>>>(feature, W1sH, W1sL,
                                                        dinv_out, h);

  k_layer1<<<N_NODES / 4, 256, 0, stream>>>(row_start, cnt_dst, src_s, w_s, h,
                                            dinv_in, dinv_out, b1, W2, g2);
  k_agg2_final<<<(N_NODES * H2 + 255) / 256, 256, 0, stream>>>(
      row_start, cnt_dst, src_s, w_s, g2, dinv_in, b2, out);
}